// Round 2
// baseline (5857.659 us; speedup 1.0000x reference)
//
#include <hip/hip_runtime.h>

// LSTM T=512, B=32, H=512, L=2. fp16 compute, fp32 accumulate/state.
// Single fused persistent kernel: 128 WGs x 128 thr (2 waves).
//   blocks 0..63  = layer 0 (x from x0h),
//   blocks 64..127= layer 1 (x = h0seq[t], pipelined on layer-0).
// Each WG owns 8 hidden cols x 4 gates; wave wv covers batches [wv*16,+16).
// Weights live in registers.
// Sync (this round): NO flags/epochs at all. h slots are pre-filled with a
// canary (fp16 2.125 = 0x4040, unreachable since |h|<1). Consumers poll the
// h data DIRECTLY with agent-scope (L2-bypassing) atomic loads and retry
// until no canary word remains. Each u32 is stored atomically by exactly one
// producer thread, so every word self-validates: no store-drain barrier, no
// flag publish, no separate detect leg. This removes two of the three
// dependent cross-chip latency legs per timestep.

typedef _Float16 half8_t __attribute__((ext_vector_type(8)));
typedef _Float16 half4_t __attribute__((ext_vector_type(4)));
typedef float f32x4 __attribute__((ext_vector_type(4)));
typedef unsigned int u32;
typedef u32 u32x4 __attribute__((ext_vector_type(4)));
typedef unsigned short u16;
typedef unsigned long long u64;

#define T_LEN 512
#define BATCH 32
#define HID 512
#define SLOT 16384           // BATCH*HID elems per timestep slot
#define LW (2048 * 512)      // per-layer weight elems
#define CANARY 0x40404040u   // two fp16 2.125 halves — impossible h value

__device__ __forceinline__ float fast_sigmoid(float x) {
  return 1.f / (1.f + __expf(-x));
}
__device__ __forceinline__ float fast_tanh(float x) {
  return 1.f - 2.f / (1.f + __expf(2.f * x));
}
__device__ __forceinline__ u32 umin_(u32 a, u32 b) { return a < b ? a : b; }

// Poll one 16-row x 512-col fp16 slot slice into af[16] (this lane's MFMA
// A-fragments) with L2-bypassing loads; retry until no canary word is seen
// anywhere in the wave. Data is valid the moment it arrives — no ordering.
__device__ __forceinline__ void poll_load_slot(const _Float16* src, int row, int q,
                                               half8_t af[16]) {
  const _Float16* base = src + row * HID + q * 8;
  for (;;) {
    u32 mn = 0xFFFFFFFFu;
#pragma unroll
    for (int kc = 0; kc < 16; ++kc) {
      union { half8_t h; u64 q2[2]; u32 w[4]; } u;
      const u64* p = (const u64*)(base + kc * 32);
      u.q2[0] = __hip_atomic_load(p, __ATOMIC_RELAXED, __HIP_MEMORY_SCOPE_AGENT);
      u.q2[1] = __hip_atomic_load(p + 1, __ATOMIC_RELAXED, __HIP_MEMORY_SCOPE_AGENT);
      af[kc] = u.h;
      mn = umin_(mn, umin_(umin_(u.w[0] ^ CANARY, u.w[1] ^ CANARY),
                           umin_(u.w[2] ^ CANARY, u.w[3] ^ CANARY)));
    }
    if (__all(mn != 0)) break;   // no lane saw a canary word
    __builtin_amdgcn_s_sleep(1);
  }
}

// ---------------- convert fp32 -> fp16 (x, Wih, Whh) + bias sum + canary fill ----
__global__ __launch_bounds__(256) void convert_k(
    const float4* __restrict__ x,    // 8388608 floats = 2097152 float4
    const float4* __restrict__ wih,  // 2097152 floats = 524288 float4
    const float4* __restrict__ whh,  // same
    const float* __restrict__ bih, const float* __restrict__ bhh,
    half4_t* __restrict__ xh, half4_t* __restrict__ wihh, half4_t* __restrict__ whhh,
    float* __restrict__ bsum,
    u32x4* __restrict__ h0fill, u32x4* __restrict__ h1fill) {  // slots 1..512
  const int N4X = 2097152, N4W = 524288, TOT = N4X + 2 * N4W;
  int gid = blockIdx.x * 256 + threadIdx.x;
  int stride = gridDim.x * 256;
  for (int i = gid; i < TOT; i += stride) {
    float4 v;
    half4_t* dst;
    if (i < N4X) { v = x[i]; dst = xh + i; }
    else if (i < N4X + N4W) { v = wih[i - N4X]; dst = wihh + (i - N4X); }
    else { v = whh[i - N4X - N4W]; dst = whhh + (i - N4X - N4W); }
    half4_t h;
    h[0] = (_Float16)v.x; h[1] = (_Float16)v.y; h[2] = (_Float16)v.z; h[3] = (_Float16)v.w;
    *dst = h;
  }
  // canary-fill slots 1..512 of both h sequences (slot 0 stays zero)
  const int NF = 512 * (SLOT / 2) / 4;  // u32x4 per buffer = 1,048,576
  u32x4 cv; cv[0] = CANARY; cv[1] = CANARY; cv[2] = CANARY; cv[3] = CANARY;
  for (int i = gid; i < 2 * NF; i += stride) {
    if (i < NF) h0fill[i] = cv; else h1fill[i - NF] = cv;
  }
  if (gid < 4096) bsum[gid] = bih[gid] + bhh[gid];
}

// ---------------- fused 2-layer pipelined recurrence ----------------
__global__ __launch_bounds__(128, 1) void lstm_fused(
    const _Float16* __restrict__ x0h,   // [T][SLOT]
    const _Float16* __restrict__ wih16, // [2][2048][512]
    const _Float16* __restrict__ whh16, // [2][2048][512]
    const float* __restrict__ bsum,     // [2][2048]
    _Float16* h0seq,                    // [T+1][SLOT], slot0 zero, rest canary
    _Float16* h1seq,                    // [T+1][SLOT], slot0 zero, rest canary
    float* outf) {                      // [T][B][H] fp32
  int bid = blockIdx.x;
  int layer = bid >> 6, wg = bid & 63;
  int tid = threadIdx.x;               // 0..127
  int ln = tid & 63;
  int q = ln >> 4, l15 = ln & 15;
  int m0 = (tid >> 6) * 16;            // wave's batch base

  // ---- persistent register weight fragments: n=32 = 4 gates x 8 cols ----
  const _Float16* wih_l = wih16 + (size_t)layer * LW;
  const _Float16* whh_l = whh16 + (size_t)layer * LW;
  half8_t wx[2][16], wh[2][16];
  float bv[2];
#pragma unroll
  for (int j = 0; j < 2; ++j) {
    int nl = j * 16 + l15;
    int grow = (nl >> 3) * 512 + wg * 8 + (nl & 7);   // gate*512 + col
    size_t ro = (size_t)grow * 512;
#pragma unroll
    for (int kc = 0; kc < 16; ++kc) {
      wx[j][kc] = *(const half8_t*)(wih_l + ro + kc * 32 + q * 8);
      wh[j][kc] = *(const half8_t*)(whh_l + ro + kc * 32 + q * 8);
    }
    bv[j] = bsum[layer * 2048 + grow];
  }

  const _Float16* xbase = layer ? (h0seq + SLOT) : x0h;  // step t reads xbase+(t-1)*SLOT
  _Float16* hself = layer ? h1seq : h0seq;

  // consumer mapping: thread -> (batch cb, col pair cp)
  int cb = tid >> 2;
  int cp = tid & 3;
  int col0 = wg * 8 + cp * 2;
  float cst0 = 0.f, cst1 = 0.f;

  __shared__ float Zs[4 * 297];  // [gate]*297 + b*9 + c   (33*9 per gate)

  for (int t = 1; t <= T_LEN; ++t) {
    const _Float16* xsrc = xbase + (size_t)(t - 1) * SLOT;
    const _Float16* hsrc = hself + (size_t)(t - 1) * SLOT;
    f32x4 acc0 = {}, acc1 = {};
    half8_t af[16];

    if (layer == 0) {
      // x-part: static input, plain cached loads — independent of sync
#pragma unroll
      for (int kc = 0; kc < 16; ++kc)
        af[kc] = *(const half8_t*)(xsrc + (m0 + l15) * HID + kc * 32 + q * 8);
#pragma unroll
      for (int kc = 0; kc < 16; ++kc) {
        acc0 = __builtin_amdgcn_mfma_f32_16x16x32_f16(af[kc], wx[0][kc], acc0, 0, 0, 0);
        acc1 = __builtin_amdgcn_mfma_f32_16x16x32_f16(af[kc], wx[1][kc], acc1, 0, 0, 0);
      }
      // h-part: self-validating canary poll (slot 0 is zeros -> passes at t=1)
      poll_load_slot(hsrc, m0 + l15, q, af);
#pragma unroll
      for (int kc = 0; kc < 16; ++kc) {
        acc0 = __builtin_amdgcn_mfma_f32_16x16x32_f16(af[kc], wh[0][kc], acc0, 0, 0, 0);
        acc1 = __builtin_amdgcn_mfma_f32_16x16x32_f16(af[kc], wh[1][kc], acc1, 0, 0, 0);
      }
    } else {
      // own h-part first (usually already available), then layer-0's output
      poll_load_slot(hsrc, m0 + l15, q, af);
#pragma unroll
      for (int kc = 0; kc < 16; ++kc) {
        acc0 = __builtin_amdgcn_mfma_f32_16x16x32_f16(af[kc], wh[0][kc], acc0, 0, 0, 0);
        acc1 = __builtin_amdgcn_mfma_f32_16x16x32_f16(af[kc], wh[1][kc], acc1, 0, 0, 0);
      }
      poll_load_slot(xsrc, m0 + l15, q, af);   // x = h0seq[t], canary-gated
#pragma unroll
      for (int kc = 0; kc < 16; ++kc) {
        acc0 = __builtin_amdgcn_mfma_f32_16x16x32_f16(af[kc], wx[0][kc], acc0, 0, 0, 0);
        acc1 = __builtin_amdgcn_mfma_f32_16x16x32_f16(af[kc], wx[1][kc], acc1, 0, 0, 0);
      }
    }

    // publish z to LDS: lane's tile j col = nl = j*16+l15 -> gate=nl>>3, c=nl&7
#pragma unroll
    for (int j = 0; j < 2; ++j) {
      int nl = j * 16 + l15, g = nl >> 3, c = nl & 7;
      const f32x4& a = j ? acc1 : acc0;
#pragma unroll
      for (int r = 0; r < 4; ++r)
        Zs[g * 297 + (m0 + q * 4 + r) * 9 + c] = a[r] + bv[j];
    }
    __syncthreads();

    // elementwise: thread owns (cb, col0, col0+1)
    float h0, h1;
    {
      float zi0 = Zs[0 * 297 + cb * 9 + cp * 2], zi1 = Zs[0 * 297 + cb * 9 + cp * 2 + 1];
      float zf0 = Zs[1 * 297 + cb * 9 + cp * 2], zf1 = Zs[1 * 297 + cb * 9 + cp * 2 + 1];
      float zg0 = Zs[2 * 297 + cb * 9 + cp * 2], zg1 = Zs[2 * 297 + cb * 9 + cp * 2 + 1];
      float zo0 = Zs[3 * 297 + cb * 9 + cp * 2], zo1 = Zs[3 * 297 + cb * 9 + cp * 2 + 1];
      float i0 = fast_sigmoid(zi0), f0 = fast_sigmoid(zf0), g0 = fast_tanh(zg0), o0 = fast_sigmoid(zo0);
      float i1 = fast_sigmoid(zi1), f1 = fast_sigmoid(zf1), g1 = fast_tanh(zg1), o1 = fast_sigmoid(zo1);
      cst0 = f0 * cst0 + i0 * g0;
      cst1 = f1 * cst1 + i1 * g1;
      h0 = o0 * fast_tanh(cst0);
      h1 = o1 * fast_tanh(cst1);
      // atomic u32 write-through store: each word self-validates vs canary,
      // so no drain/publish ordering is needed anywhere.
      u32 hp = (u32)__builtin_bit_cast(u16, (_Float16)h0) |
               ((u32)__builtin_bit_cast(u16, (_Float16)h1) << 16);
      u32* hdst = (u32*)(hself + (size_t)t * SLOT + cb * HID + col0);
      __hip_atomic_store(hdst, hp, __ATOMIC_RELAXED, __HIP_MEMORY_SCOPE_AGENT);
    }
    // barrier only to protect Zs reuse next iteration (elementwise reads vs
    // next step's writes) — NOT a store-drain requirement anymore
    __syncthreads();
    // out store — nobody consumes it; drain overlaps next step
    if (layer) {
      float2 o2; o2.x = h0; o2.y = h1;
      *(float2*)(outf + (size_t)(t - 1) * SLOT + cb * HID + col0) = o2;
    }
  }
}

extern "C" void kernel_launch(void* const* d_in, const int* in_sizes, int n_in,
                              void* d_out, int out_size, void* d_ws, size_t ws_size,
                              hipStream_t stream) {
  const float* x = (const float*)d_in[0];
  const float* Wih = (const float*)d_in[1];
  const float* Whh = (const float*)d_in[2];
  const float* bih = (const float*)d_in[3];
  const float* bhh = (const float*)d_in[4];
  char* ws = (char*)d_ws;
  // ws layout (bytes)
  const size_t OFF_X0H = 0;                  // 16,777,216
  const size_t OFF_H0SEQ = 16777216;         // 513*32768 = 16,809,984
  const size_t OFF_H1SEQ = 33587200;         // 16,809,984
  const size_t OFF_WIH = 50397184;           // 4,194,304
  const size_t OFF_WHH = 54591488;           // 4,194,304
  const size_t OFF_BSUM = 58785792;          // 16,384
  const size_t TOTAL = 58802688;
  if (ws_size < TOTAL) return;
  _Float16* x0h = (_Float16*)(ws + OFF_X0H);
  _Float16* h0seq = (_Float16*)(ws + OFF_H0SEQ);
  _Float16* h1seq = (_Float16*)(ws + OFF_H1SEQ);
  _Float16* wihh = (_Float16*)(ws + OFF_WIH);
  _Float16* whhh = (_Float16*)(ws + OFF_WHH);
  float* bsum = (float*)(ws + OFF_BSUM);

  // zero slot 0 of both h sequences (initial h state); visible to the fused
  // kernel's bypass loads via inter-dispatch release/acquire
  hipMemsetAsync(ws + OFF_H0SEQ, 0, 32768, stream);
  hipMemsetAsync(ws + OFF_H1SEQ, 0, 32768, stream);
  convert_k<<<3072, 256, 0, stream>>>((const float4*)x, (const float4*)Wih,
                                      (const float4*)Whh, bih, bhh,
                                      (half4_t*)x0h, (half4_t*)wihh, (half4_t*)whhh, bsum,
                                      (u32x4*)(h0seq + SLOT), (u32x4*)(h1seq + SLOT));
  lstm_fused<<<128, 128, 0, stream>>>(x0h, wihh, whhh, bsum, h0seq, h1seq,
                                      (float*)d_out);
}

// Round 6
// 3439.788 us; speedup vs baseline: 1.7029x; 1.7029x over previous
//
#include <hip/hip_runtime.h>

// LSTM T=512, B=32, H=512, L=2. fp16 compute, fp32 accumulate/state.
// Single fused persistent kernel: 128 WGs x 128 thr (2 waves).
//   blocks 0..63  = layer 0 (x from x0h),
//   blocks 64..127= layer 1 (x = h0seq[t], pipelined on layer-0 epoch).
// Each WG owns 8 hidden cols x 4 gates (n=32 per wave as 4 gates x 8 cols);
// wave wv covers batches [wv*16, wv*16+16).
// Sync: per-WG flag array (R1, passed). WG g stores flags[g]=t after a
// vmcnt-drained barrier; consumers poll 64 flags with 64 parallel lane loads,
// exit via __all(flag >= t).
// THIS ROUND's single change vs R1: weight fragments are forced
// register-resident. R1's VGPR_Count=176 < the 256 VGPRs the weight set
// needs, proving the compiler rematerialized the weight loads inside the
// t-loop (re-streaming ~1KB/thread/step from L2, serially after the flag
// wait). Each loaded fragment is passed through a no-op asm ("+v"), making
// the value asm-defined: rematerialization becomes impossible and the
// allocator must keep it in VGPRs (launch_bounds(128,1) allows ~512).

typedef _Float16 half8_t __attribute__((ext_vector_type(8)));
typedef _Float16 half4_t __attribute__((ext_vector_type(4)));
typedef float f32x4 __attribute__((ext_vector_type(4)));
typedef unsigned int u32;
typedef unsigned short u16;

#define T_LEN 512
#define BATCH 32
#define HID 512
#define SLOT 16384           // BATCH*HID elems per timestep slot
#define LW (2048 * 512)      // per-layer weight elems

__device__ __forceinline__ float fast_sigmoid(float x) {
  return 1.f / (1.f + __expf(-x));
}
__device__ __forceinline__ float fast_tanh(float x) {
  return 1.f - 2.f / (1.f + __expf(2.f * x));
}

// Poll 64-entry flag array: done when flags[ln] >= tgt for every lane 0..63.
// self >= 0 exempts that lane (own WG: locally known done).
__device__ __forceinline__ void wait_flags(const u32* flags, int ln, u32 tgt, int self) {
  for (;;) {
    u32 v = __hip_atomic_load(flags + ln, __ATOMIC_RELAXED, __HIP_MEMORY_SCOPE_AGENT);
    if (__all((int)(v >= tgt) | (int)(ln == self))) break;
    __builtin_amdgcn_s_sleep(1);
  }
  asm volatile("" ::: "memory");
}

// ---------------- convert fp32 -> fp16 (x, Wih, Whh) + bias sum ----------------
__global__ __launch_bounds__(256) void convert_k(
    const float4* __restrict__ x,    // 8388608 floats = 2097152 float4
    const float4* __restrict__ wih,  // 2097152 floats = 524288 float4
    const float4* __restrict__ whh,  // same
    const float* __restrict__ bih, const float* __restrict__ bhh,
    half4_t* __restrict__ xh, half4_t* __restrict__ wihh, half4_t* __restrict__ whhh,
    float* __restrict__ bsum) {
  const int N4X = 2097152, N4W = 524288, TOT = N4X + 2 * N4W;
  int gid = blockIdx.x * 256 + threadIdx.x;
  for (int i = gid; i < TOT; i += gridDim.x * 256) {
    float4 v;
    half4_t* dst;
    if (i < N4X) { v = x[i]; dst = xh + i; }
    else if (i < N4X + N4W) { v = wih[i - N4X]; dst = wihh + (i - N4X); }
    else { v = whh[i - N4X - N4W]; dst = whhh + (i - N4X - N4W); }
    half4_t h;
    h[0] = (_Float16)v.x; h[1] = (_Float16)v.y; h[2] = (_Float16)v.z; h[3] = (_Float16)v.w;
    *dst = h;
  }
  if (gid < 4096) bsum[gid] = bih[gid] + bhh[gid];
}

// ---------------- fused 2-layer pipelined recurrence ----------------
__global__ __launch_bounds__(128, 1) void lstm_fused(
    const _Float16* __restrict__ x0h,   // [T][SLOT]
    const _Float16* __restrict__ wih16, // [2][2048][512]
    const _Float16* __restrict__ whh16, // [2][2048][512]
    const float* __restrict__ bsum,     // [2][2048]
    _Float16* h0seq,                    // [T+1][SLOT], slot0 zeroed
    _Float16* h1seq,                    // [T+1][SLOT], slot0 zeroed
    u32* flags0, u32* flags1,           // 64 u32 each, zeroed
    float* outf) {                      // [T][B][H] fp32
  int bid = blockIdx.x;
  int layer = bid >> 6, wg = bid & 63;
  int tid = threadIdx.x;               // 0..127
  int ln = tid & 63;
  int q = ln >> 4, l15 = ln & 15;
  int m0 = (tid >> 6) * 16;            // wave's batch base

  // ---- persistent register weight fragments: n=32 = 4 gates x 8 cols ----
  // Each fragment passes through a no-op asm => value is asm-defined =>
  // cannot be rematerialized from memory inside the t-loop.
  const _Float16* wih_l = wih16 + (size_t)layer * LW;
  const _Float16* whh_l = whh16 + (size_t)layer * LW;
  half8_t wx0[16], wx1[16], wh0[16], wh1[16];
  float bv[2];
#pragma unroll
  for (int j = 0; j < 2; ++j) {
    int nl = j * 16 + l15;
    int grow = (nl >> 3) * 512 + wg * 8 + (nl & 7);   // gate*512 + col
    size_t ro = (size_t)grow * 512;
#pragma unroll
    for (int kc = 0; kc < 16; ++kc) {
      half8_t a = *(const half8_t*)(wih_l + ro + kc * 32 + q * 8);
      half8_t b = *(const half8_t*)(whh_l + ro + kc * 32 + q * 8);
      asm volatile("" : "+v"(a));
      asm volatile("" : "+v"(b));
      if (j == 0) { wx0[kc] = a; wh0[kc] = b; }
      else        { wx1[kc] = a; wh1[kc] = b; }
    }
    bv[j] = bsum[layer * 2048 + grow];
  }

  const _Float16* xbase = layer ? (h0seq + SLOT) : x0h;  // step t reads xbase+(t-1)*SLOT
  _Float16* hself = layer ? h1seq : h0seq;
  u32* fself = layer ? flags1 : flags0;

  // consumer mapping: thread -> (batch cb, col pair cp)
  int cb = tid >> 2;
  int cp = tid & 3;
  int col0 = wg * 8 + cp * 2;
  float cst0 = 0.f, cst1 = 0.f;

  __shared__ float Zs[4 * 297];  // [gate]*297 + b*9 + c   (33*9 per gate)

  for (int t = 1; t <= T_LEN; ++t) {
    const _Float16* xsrc = xbase + (size_t)(t - 1) * SLOT;
    const _Float16* hsrc = hself + (size_t)(t - 1) * SLOT;
    f32x4 acc0 = {}, acc1 = {};
    half8_t af[16];

    if (layer == 0) {
      // x-part: independent of sync — do before waiting
#pragma unroll
      for (int kc = 0; kc < 16; ++kc)
        af[kc] = *(const half8_t*)(xsrc + (m0 + l15) * HID + kc * 32 + q * 8);
#pragma unroll
      for (int kc = 0; kc < 16; ++kc) {
        acc0 = __builtin_amdgcn_mfma_f32_16x16x32_f16(af[kc], wx0[kc], acc0, 0, 0, 0);
        acc1 = __builtin_amdgcn_mfma_f32_16x16x32_f16(af[kc], wx1[kc], acc1, 0, 0, 0);
      }
      if (t > 1) wait_flags(flags0, ln, (u32)(t - 1), wg);
      // h-part
#pragma unroll
      for (int kc = 0; kc < 16; ++kc)
        af[kc] = *(const half8_t*)(hsrc + (m0 + l15) * HID + kc * 32 + q * 8);
#pragma unroll
      for (int kc = 0; kc < 16; ++kc) {
        acc0 = __builtin_amdgcn_mfma_f32_16x16x32_f16(af[kc], wh0[kc], acc0, 0, 0, 0);
        acc1 = __builtin_amdgcn_mfma_f32_16x16x32_f16(af[kc], wh1[kc], acc1, 0, 0, 0);
      }
    } else {
      // own h-part first: only needs own layer's step t-1 (usually ready)
      if (t > 1) wait_flags(flags1, ln, (u32)(t - 1), wg);
#pragma unroll
      for (int kc = 0; kc < 16; ++kc)
        af[kc] = *(const half8_t*)(hsrc + (m0 + l15) * HID + kc * 32 + q * 8);
#pragma unroll
      for (int kc = 0; kc < 16; ++kc) {
        acc0 = __builtin_amdgcn_mfma_f32_16x16x32_f16(af[kc], wh0[kc], acc0, 0, 0, 0);
        acc1 = __builtin_amdgcn_mfma_f32_16x16x32_f16(af[kc], wh1[kc], acc1, 0, 0, 0);
      }
      // now wait for layer 0 to finish step t (x = h0seq[t])
      wait_flags(flags0, ln, (u32)t, -1);
#pragma unroll
      for (int kc = 0; kc < 16; ++kc)
        af[kc] = *(const half8_t*)(xsrc + (m0 + l15) * HID + kc * 32 + q * 8);
#pragma unroll
      for (int kc = 0; kc < 16; ++kc) {
        acc0 = __builtin_amdgcn_mfma_f32_16x16x32_f16(af[kc], wx0[kc], acc0, 0, 0, 0);
        acc1 = __builtin_amdgcn_mfma_f32_16x16x32_f16(af[kc], wx1[kc], acc1, 0, 0, 0);
      }
    }

    // publish z to LDS: lane's tile j col = nl = j*16+l15 -> gate=nl>>3, c=nl&7
#pragma unroll
    for (int j = 0; j < 2; ++j) {
      int nl = j * 16 + l15, g = nl >> 3, c = nl & 7;
      const f32x4& a = j ? acc1 : acc0;
#pragma unroll
      for (int r = 0; r < 4; ++r)
        Zs[g * 297 + (m0 + q * 4 + r) * 9 + c] = a[r] + bv[j];
    }
    __syncthreads();

    // elementwise: thread owns (cb, col0, col0+1)
    float h0, h1;
    {
      float zi0 = Zs[0 * 297 + cb * 9 + cp * 2], zi1 = Zs[0 * 297 + cb * 9 + cp * 2 + 1];
      float zf0 = Zs[1 * 297 + cb * 9 + cp * 2], zf1 = Zs[1 * 297 + cb * 9 + cp * 2 + 1];
      float zg0 = Zs[2 * 297 + cb * 9 + cp * 2], zg1 = Zs[2 * 297 + cb * 9 + cp * 2 + 1];
      float zo0 = Zs[3 * 297 + cb * 9 + cp * 2], zo1 = Zs[3 * 297 + cb * 9 + cp * 2 + 1];
      float i0 = fast_sigmoid(zi0), f0 = fast_sigmoid(zf0), g0 = fast_tanh(zg0), o0 = fast_sigmoid(zo0);
      float i1 = fast_sigmoid(zi1), f1 = fast_sigmoid(zf1), g1 = fast_tanh(zg1), o1 = fast_sigmoid(zo1);
      cst0 = f0 * cst0 + i0 * g0;
      cst1 = f1 * cst1 + i1 * g1;
      h0 = o0 * fast_tanh(cst0);
      h1 = o1 * fast_tanh(cst1);
      // write-through packed h store (drained by the __syncthreads below
      // before the flag publish)
      u32 hp = (u32)__builtin_bit_cast(u16, (_Float16)h0) |
               ((u32)__builtin_bit_cast(u16, (_Float16)h1) << 16);
      u32* hdst = (u32*)(hself + (size_t)t * SLOT + cb * HID + col0);
      __hip_atomic_store(hdst, hp, __ATOMIC_RELAXED, __HIP_MEMORY_SCOPE_AGENT);
    }
    // drains each thread's vmcnt (incl. the h store) before the publish
    __syncthreads();
    if (tid == 0)
      __hip_atomic_store(fself + wg, (u32)t, __ATOMIC_RELAXED, __HIP_MEMORY_SCOPE_AGENT);
    // out store AFTER publish — nobody consumes it; drain overlaps next step
    if (layer) {
      float2 o2; o2.x = h0; o2.y = h1;
      *(float2*)(outf + (size_t)(t - 1) * SLOT + cb * HID + col0) = o2;
    }
  }
}

extern "C" void kernel_launch(void* const* d_in, const int* in_sizes, int n_in,
                              void* d_out, int out_size, void* d_ws, size_t ws_size,
                              hipStream_t stream) {
  const float* x = (const float*)d_in[0];
  const float* Wih = (const float*)d_in[1];
  const float* Whh = (const float*)d_in[2];
  const float* bih = (const float*)d_in[3];
  const float* bhh = (const float*)d_in[4];
  char* ws = (char*)d_ws;
  // ws layout (bytes)
  const size_t OFF_X0H = 0;                  // 16,777,216
  const size_t OFF_H0SEQ = 16777216;         // 513*32768 = 16,809,984
  const size_t OFF_H1SEQ = 33587200;         // 16,809,984
  const size_t OFF_WIH = 50397184;           // 4,194,304
  const size_t OFF_WHH = 54591488;           // 4,194,304
  const size_t OFF_BSUM = 58785792;          // 16,384
  const size_t OFF_FLAGS0 = 58802176;        // 64 u32 = 256B
  const size_t OFF_FLAGS1 = 58802432;        // 64 u32 = 256B
  const size_t TOTAL = 58802688;
  if (ws_size < TOTAL) return;
  _Float16* x0h = (_Float16*)(ws + OFF_X0H);
  _Float16* h0seq = (_Float16*)(ws + OFF_H0SEQ);
  _Float16* h1seq = (_Float16*)(ws + OFF_H1SEQ);
  _Float16* wihh = (_Float16*)(ws + OFF_WIH);
  _Float16* whhh = (_Float16*)(ws + OFF_WHH);
  float* bsum = (float*)(ws + OFF_BSUM);
  u32* flags0 = (u32*)(ws + OFF_FLAGS0);
  u32* flags1 = (u32*)(ws + OFF_FLAGS1);

  // zero: flags + slot0 of both h sequences
  hipMemsetAsync(ws + OFF_FLAGS0, 0, 512, stream);
  hipMemsetAsync(ws + OFF_H0SEQ, 0, 32768, stream);
  hipMemsetAsync(ws + OFF_H1SEQ, 0, 32768, stream);
  convert_k<<<3072, 256, 0, stream>>>((const float4*)x, (const float4*)Wih,
                                      (const float4*)Whh, bih, bhh,
                                      (half4_t*)x0h, (half4_t*)wihh, (half4_t*)whhh, bsum);
  lstm_fused<<<128, 128, 0, stream>>>(x0h, wihh, whhh, bsum, h0seq, h1seq,
                                      flags0, flags1, (float*)d_out);
}

// Round 7
// 3014.289 us; speedup vs baseline: 1.9433x; 1.1412x over previous
//
#include <hip/hip_runtime.h>

// LSTM T=512, B=32, H=512, L=2. fp16 compute, fp32 accumulate/state.
// Single fused persistent kernel: 128 WGs x 128 thr (2 waves).
//   blocks 0..63  = layer 0 (x from x0h), blocks 64..127 = layer 1.
// R1 compute skeleton. Sync rebuilt as DATA-AS-SIGNAL with 1-word gates:
//   - h slots canary-prefilled (fp16 2.125 = 0x4040, unreachable: |h|<=1).
//   - producer threads store their h u32 (agent scope) and NOTHING else:
//     no drain, no barrier, no flag. Publish cost = 0 legs.
//   - consumer lane ln polls ONE u32 (the word of WG ln, row m0, col 8*ln)
//     until != canary, then gang-loads its fragment once (agent u64 loads)
//     and canary-validates; retries only cover the store-skew window.
//   Per-step chain: store-visible (1 RTT) + detect (~1 RTT) + gang (1 RTT)
//   vs R1's 4.5 RTT (drain + flag + detect + fetch).
// Barrier-free loop: the Zs gate exchange is intra-wave (wave w writes rows
// 16w..16w+15; its elementwise threads read exactly those rows) -> both
// __syncthreads replaced by s_waitcnt lgkmcnt(0).
// L1 speculatively issues the x = h0[t] gang-load at step start (unchecked)
// and validates after its own-h MFMA: L0 runs ahead, so the LLC fetch hides.

typedef _Float16 half8_t __attribute__((ext_vector_type(8)));
typedef _Float16 half4_t __attribute__((ext_vector_type(4)));
typedef float f32x4 __attribute__((ext_vector_type(4)));
typedef unsigned int u32;
typedef u32 u32x4_t __attribute__((ext_vector_type(4)));
typedef unsigned short u16;
typedef unsigned long long u64;

#define T_LEN 512
#define BATCH 32
#define HID 512
#define SLOT 16384           // BATCH*HID elems per timestep slot
#define LW (2048 * 512)      // per-layer weight elems
#define CANARY 0x40404040u   // two fp16 2.125 halves — impossible h value

__device__ __forceinline__ float fast_sigmoid(float x) {
  return 1.f / (1.f + __expf(-x));
}
__device__ __forceinline__ float fast_tanh(float x) {
  return 1.f - 2.f / (1.f + __expf(2.f * x));
}

__device__ __forceinline__ u32 load_agent(const u32* p) {
  return __hip_atomic_load(p, __ATOMIC_RELAXED, __HIP_MEMORY_SCOPE_AGENT);
}

// 1-word-per-lane readiness gate: lane ln polls the u32 written by WG ln's
// (row m0, cp 0) producer thread. Tiny traffic (64 dwords per wave per poll).
__device__ __forceinline__ void gate_wait(const u32* gate) {
  while (!__all((int)(load_agent(gate) != CANARY))) __builtin_amdgcn_s_sleep(1);
  asm volatile("" ::: "memory");
}

// Raw gang load of one lane's 256B fragment (16 chunks x 16B) via agent-scope
// u64 loads (L1-bypassing). NO inspection here — the canary check is a
// separate pass so the compiler can defer s_waitcnt to the check site
// (enables speculative issue).
__device__ __forceinline__ void gang_raw(const _Float16* base, half8_t af[16]) {
#pragma unroll
  for (int kc = 0; kc < 16; ++kc) {
    const u64* p = (const u64*)(base + kc * 32);
    union { u64 q2[2]; half8_t h; } u;
    u.q2[0] = __hip_atomic_load(p, __ATOMIC_RELAXED, __HIP_MEMORY_SCOPE_AGENT);
    u.q2[1] = __hip_atomic_load(p + 1, __ATOMIC_RELAXED, __HIP_MEMORY_SCOPE_AGENT);
    af[kc] = u.h;
  }
}
__device__ __forceinline__ u32 check_bad(const half8_t af[16]) {
  u32 bad = 0;
#pragma unroll
  for (int kc = 0; kc < 16; ++kc) {
    union { half8_t h; u32 w[4]; } u; u.h = af[kc];
    bad |= (u32)(u.w[0] == CANARY) | (u32)(u.w[1] == CANARY) |
           (u32)(u.w[2] == CANARY) | (u32)(u.w[3] == CANARY);
  }
  return bad;
}
// gang + validate + bounded retry (store-skew window only, since callers
// gate first or speculate on long-published data)
__device__ __forceinline__ void gang_checked(const _Float16* base, half8_t af[16]) {
  gang_raw(base, af);
  u32 bad = check_bad(af);
  while (__any((int)bad)) {
    __builtin_amdgcn_s_sleep(1);
    gang_raw(base, af);
    bad = check_bad(af);
  }
}

// ---------------- convert fp32 -> fp16 (x, Wih, Whh) + bias sum + canary fill ----
__global__ __launch_bounds__(256) void convert_k(
    const float4* __restrict__ x,    // 8388608 floats = 2097152 float4
    const float4* __restrict__ wih,  // 2097152 floats = 524288 float4
    const float4* __restrict__ whh,  // same
    const float* __restrict__ bih, const float* __restrict__ bhh,
    half4_t* __restrict__ xh, half4_t* __restrict__ wihh, half4_t* __restrict__ whhh,
    float* __restrict__ bsum,
    u32x4_t* __restrict__ h0fill, u32x4_t* __restrict__ h1fill) {  // slots 1..512
  const int N4X = 2097152, N4W = 524288, TOT = N4X + 2 * N4W;
  int gid = blockIdx.x * 256 + threadIdx.x;
  int stride = gridDim.x * 256;
  for (int i = gid; i < TOT; i += stride) {
    float4 v;
    half4_t* dst;
    if (i < N4X) { v = x[i]; dst = xh + i; }
    else if (i < N4X + N4W) { v = wih[i - N4X]; dst = wihh + (i - N4X); }
    else { v = whh[i - N4X - N4W]; dst = whhh + (i - N4X - N4W); }
    half4_t h;
    h[0] = (_Float16)v.x; h[1] = (_Float16)v.y; h[2] = (_Float16)v.z; h[3] = (_Float16)v.w;
    *dst = h;
  }
  // canary-fill slots 1..512 of both h sequences (slot 0 stays zero)
  const int NF = 512 * (SLOT / 2) / 4;  // 1,048,576 u32x4 per buffer
  u32x4_t cv; cv[0] = CANARY; cv[1] = CANARY; cv[2] = CANARY; cv[3] = CANARY;
  for (int i = gid; i < 2 * NF; i += stride) {
    if (i < NF) h0fill[i] = cv; else h1fill[i - NF] = cv;
  }
  if (gid < 4096) bsum[gid] = bih[gid] + bhh[gid];
}

// ---------------- fused 2-layer pipelined recurrence (barrier-free) ----------
__global__ __launch_bounds__(128, 1) void lstm_fused(
    const _Float16* __restrict__ x0h,   // [T][SLOT]
    const _Float16* __restrict__ wih16, // [2][2048][512]
    const _Float16* __restrict__ whh16, // [2][2048][512]
    const float* __restrict__ bsum,     // [2][2048]
    _Float16* h0seq,                    // [T+1][SLOT], slot0 zero, rest canary
    _Float16* h1seq,                    // [T+1][SLOT], slot0 zero, rest canary
    float* outf) {                      // [T][B][H] fp32
  int bid = blockIdx.x;
  int layer = bid >> 6, wg = bid & 63;
  int tid = threadIdx.x;               // 0..127
  int ln = tid & 63;
  int q = ln >> 4, l15 = ln & 15;
  int m0 = (tid >> 6) * 16;            // wave's batch base

  // ---- persistent weight fragments: n=32 = 4 gates x 8 cols (land in AGPRs) ----
  const _Float16* wih_l = wih16 + (size_t)layer * LW;
  const _Float16* whh_l = whh16 + (size_t)layer * LW;
  half8_t wx[2][16], wh[2][16];
  float bv[2];
#pragma unroll
  for (int j = 0; j < 2; ++j) {
    int nl = j * 16 + l15;
    int grow = (nl >> 3) * 512 + wg * 8 + (nl & 7);   // gate*512 + col
    size_t ro = (size_t)grow * 512;
#pragma unroll
    for (int kc = 0; kc < 16; ++kc) {
      wx[j][kc] = *(const half8_t*)(wih_l + ro + kc * 32 + q * 8);
      wh[j][kc] = *(const half8_t*)(whh_l + ro + kc * 32 + q * 8);
    }
    bv[j] = bsum[layer * 2048 + grow];
  }

  _Float16* hself = layer ? h1seq : h0seq;

  // consumer mapping: thread -> (batch cb, col pair cp)
  int cb = tid >> 2;
  int cp = tid & 3;
  int col0 = wg * 8 + cp * 2;
  float cst0 = 0.f, cst1 = 0.f;
  const int fragoff = (m0 + l15) * HID + q * 8;   // lane's fragment base in a slot
  const int gateoff = m0 * HID + ln * 8;          // lane's gate word in a slot

  __shared__ float Zs[4 * 297];  // [gate]*297 + b*9 + c (rows disjoint by wave)

  for (int t = 1; t <= T_LEN; ++t) {
    const _Float16* hsrc = hself + (size_t)(t - 1) * SLOT;
    f32x4 acc0 = {}, acc1 = {};
    half8_t af[16];

    if (layer == 0) {
      // x-part: static input, plain cached loads — wait absorbs its latency
      const _Float16* xsrc = x0h + (size_t)(t - 1) * SLOT + fragoff;
#pragma unroll
      for (int kc = 0; kc < 16; ++kc) af[kc] = *(const half8_t*)(xsrc + kc * 32);
#pragma unroll
      for (int kc = 0; kc < 16; ++kc) {
        acc0 = __builtin_amdgcn_mfma_f32_16x16x32_f16(af[kc], wx[0][kc], acc0, 0, 0, 0);
        acc1 = __builtin_amdgcn_mfma_f32_16x16x32_f16(af[kc], wx[1][kc], acc1, 0, 0, 0);
      }
      // h-part: gate (1 word/lane) then single validated gang-load
      gate_wait((const u32*)(hsrc + gateoff));
      gang_checked(hsrc + fragoff, af);
#pragma unroll
      for (int kc = 0; kc < 16; ++kc) {
        acc0 = __builtin_amdgcn_mfma_f32_16x16x32_f16(af[kc], wh[0][kc], acc0, 0, 0, 0);
        acc1 = __builtin_amdgcn_mfma_f32_16x16x32_f16(af[kc], wh[1][kc], acc1, 0, 0, 0);
      }
    } else {
      // x = h0seq[t]; speculatively ISSUE the gang now (no check yet — the
      // canary check below is where the compiler places the s_waitcnt)
      const _Float16* xsrc = h0seq + (size_t)t * SLOT;
      half8_t xf[16];
      gang_raw(xsrc + fragoff, xf);
      // own h-part (the tight self-recurrence edge)
      gate_wait((const u32*)(hsrc + gateoff));
      gang_checked(hsrc + fragoff, af);
#pragma unroll
      for (int kc = 0; kc < 16; ++kc) {
        acc0 = __builtin_amdgcn_mfma_f32_16x16x32_f16(af[kc], wh[0][kc], acc0, 0, 0, 0);
        acc1 = __builtin_amdgcn_mfma_f32_16x16x32_f16(af[kc], wh[1][kc], acc1, 0, 0, 0);
      }
      // validate the speculative x data; rare fallback: gate + reload
      u32 xbad = check_bad(xf);
      if (__any((int)xbad)) {
        gate_wait((const u32*)(xsrc + gateoff));
        gang_checked(xsrc + fragoff, xf);
      }
#pragma unroll
      for (int kc = 0; kc < 16; ++kc) {
        acc0 = __builtin_amdgcn_mfma_f32_16x16x32_f16(xf[kc], wx[0][kc], acc0, 0, 0, 0);
        acc1 = __builtin_amdgcn_mfma_f32_16x16x32_f16(xf[kc], wx[1][kc], acc1, 0, 0, 0);
      }
    }

    // publish z to LDS: lane's tile j col = nl = j*16+l15 -> gate=nl>>3, c=nl&7
    // Rows written (m0 + q*4 + r) == rows read by this wave's elementwise
    // threads (cb = tid>>2 spans m0..m0+15) -> intra-wave: lgkmcnt, no barrier.
#pragma unroll
    for (int j = 0; j < 2; ++j) {
      int nl = j * 16 + l15, g = nl >> 3, c = nl & 7;
      const f32x4& a = j ? acc1 : acc0;
#pragma unroll
      for (int r = 0; r < 4; ++r)
        Zs[g * 297 + (m0 + q * 4 + r) * 9 + c] = a[r] + bv[j];
    }
    asm volatile("s_waitcnt lgkmcnt(0)" ::: "memory");

    // elementwise: thread owns (cb, col0, col0+1)
    float h0, h1;
    {
      float zi0 = Zs[0 * 297 + cb * 9 + cp * 2], zi1 = Zs[0 * 297 + cb * 9 + cp * 2 + 1];
      float zf0 = Zs[1 * 297 + cb * 9 + cp * 2], zf1 = Zs[1 * 297 + cb * 9 + cp * 2 + 1];
      float zg0 = Zs[2 * 297 + cb * 9 + cp * 2], zg1 = Zs[2 * 297 + cb * 9 + cp * 2 + 1];
      float zo0 = Zs[3 * 297 + cb * 9 + cp * 2], zo1 = Zs[3 * 297 + cb * 9 + cp * 2 + 1];
      float i0 = fast_sigmoid(zi0), f0 = fast_sigmoid(zf0), g0 = fast_tanh(zg0), o0 = fast_sigmoid(zo0);
      float i1 = fast_sigmoid(zi1), f1 = fast_sigmoid(zf1), g1 = fast_tanh(zg1), o1 = fast_sigmoid(zo1);
      cst0 = f0 * cst0 + i0 * g0;
      cst1 = f1 * cst1 + i1 * g1;
      h0 = o0 * fast_tanh(cst0);
      h1 = o1 * fast_tanh(cst1);
      // fire-and-forget atomic u32 h store: the word itself is the signal
      u32 hp = (u32)__builtin_bit_cast(u16, (_Float16)h0) |
               ((u32)__builtin_bit_cast(u16, (_Float16)h1) << 16);
      u32* hdst = (u32*)(hself + (size_t)t * SLOT + cb * HID + col0);
      __hip_atomic_store(hdst, hp, __ATOMIC_RELAXED, __HIP_MEMORY_SCOPE_AGENT);
    }
    // WAR fence: elementwise Zs reads retired before next iteration's writes
    asm volatile("s_waitcnt lgkmcnt(0)" ::: "memory");
    // out store — nobody consumes it; drains during the next step
    if (layer) {
      float2 o2; o2.x = h0; o2.y = h1;
      *(float2*)(outf + (size_t)(t - 1) * SLOT + cb * HID + col0) = o2;
    }
  }
}

extern "C" void kernel_launch(void* const* d_in, const int* in_sizes, int n_in,
                              void* d_out, int out_size, void* d_ws, size_t ws_size,
                              hipStream_t stream) {
  const float* x = (const float*)d_in[0];
  const float* Wih = (const float*)d_in[1];
  const float* Whh = (const float*)d_in[2];
  const float* bih = (const float*)d_in[3];
  const float* bhh = (const float*)d_in[4];
  char* ws = (char*)d_ws;
  // ws layout (bytes) — identical to R1's proven budget
  const size_t OFF_X0H = 0;                  // 16,777,216
  const size_t OFF_H0SEQ = 16777216;         // 513*32768 = 16,809,984
  const size_t OFF_H1SEQ = 33587200;         // 16,809,984
  const size_t OFF_WIH = 50397184;           // 4,194,304
  const size_t OFF_WHH = 54591488;           // 4,194,304
  const size_t OFF_BSUM = 58785792;          // 16,384
  const size_t TOTAL = 58802688;
  if (ws_size < TOTAL) return;
  _Float16* x0h = (_Float16*)(ws + OFF_X0H);
  _Float16* h0seq = (_Float16*)(ws + OFF_H0SEQ);
  _Float16* h1seq = (_Float16*)(ws + OFF_H1SEQ);
  _Float16* wihh = (_Float16*)(ws + OFF_WIH);
  _Float16* whhh = (_Float16*)(ws + OFF_WHH);
  float* bsum = (float*)(ws + OFF_BSUM);

  // zero slot 0 of both h sequences (initial h state)
  hipMemsetAsync(ws + OFF_H0SEQ, 0, 32768, stream);
  hipMemsetAsync(ws + OFF_H1SEQ, 0, 32768, stream);
  convert_k<<<3072, 256, 0, stream>>>((const float4*)x, (const float4*)Wih,
                                      (const float4*)Whh, bih, bhh,
                                      (half4_t*)x0h, (half4_t*)wihh, (half4_t*)whhh, bsum,
                                      (u32x4_t*)(h0seq + SLOT), (u32x4_t*)(h1seq + SLOT));
  lstm_fused<<<128, 128, 0, stream>>>(x0h, wihh, whhh, bsum, h0seq, h1seq,
                                      (float*)d_out);
}